// Round 13
// baseline (334.550 us; speedup 1.0000x reference)
//
#include <hip/hip_runtime.h>

typedef unsigned short u16;
using bf16x8 = __attribute__((ext_vector_type(8))) __bf16;
using f32x4  = __attribute__((ext_vector_type(4))) float;

// SCALE * log2(e): softmax runs in exp2 domain
#define QSCALE 0.18033688011f

#define EXP2F(x) __builtin_amdgcn_exp2f(x)
#define SCHED_FENCE() __builtin_amdgcn_sched_barrier(0)

__device__ __forceinline__ u16 f2bf(float f) {
  union { float f; unsigned int u; } x; x.f = f;
  unsigned int r = x.u + 0x7FFFu + ((x.u >> 16) & 1u);
  return (u16)(r >> 16);
}

__device__ __forceinline__ bf16x8 ld8(const u16* p) {
  return *reinterpret_cast<const bf16x8*>(p);
}

__device__ __forceinline__ void gload16(const u16* g, u16* l) {
  __builtin_amdgcn_global_load_lds(
      (const __attribute__((address_space(1))) unsigned int*)g,
      (__attribute__((address_space(3))) unsigned int*)l, 16, 0, 0);
}

__global__ void cast4_f32_to_bf16(const float* __restrict__ a, const float* __restrict__ b,
                                  const float* __restrict__ c, const float* __restrict__ d,
                                  u16* __restrict__ out, int n4) {
  const int y = blockIdx.y;
  const int i = blockIdx.x * 256 + threadIdx.x;
  if (i >= n4) return;
  const float* src = (y == 0) ? a : (y == 1) ? b : (y == 2) ? c : d;
  const float4 v = reinterpret_cast<const float4*>(src)[i];
  ushort4 o;
  o.x = f2bf(v.x); o.y = f2bf(v.y); o.z = f2bf(v.z); o.w = f2bf(v.w);
  reinterpret_cast<ushort4*>(out + (size_t)y * n4 * 4)[i] = o;
}

// ---- shared GEMM core (m97 structure: 128x128 tile, BK=32, gload_lds w=16) ----
// bx/by supplied by caller (XCD-swizzled). Known-good shape; unchanged.
#define GEMM_CORE(A_, B_, K_, BX_, BY_)                                              \
  __shared__ alignas(16) u16 lds_a[128 * 32];                                        \
  __shared__ alignas(16) u16 lds_b[128 * 32];                                        \
  const int t = threadIdx.x;                                                         \
  const int w = t >> 6, lane = t & 63;                                               \
  const int wr = w >> 1, wc = w & 1;                                                 \
  const size_t row0 = (size_t)(BY_) * 128;                                           \
  const size_t col0 = (size_t)(BX_) * 128;                                           \
  f32x4 acc[4][4];                                                                   \
  _Pragma("unroll") for (int i = 0; i < 4; ++i)                                      \
    _Pragma("unroll") for (int j = 0; j < 4; ++j) acc[i][j] = {0.f, 0.f, 0.f, 0.f};  \
  const u16* ga = A_ + (row0 + (t >> 2)) * K_ + (t & 3) * 8;                         \
  const u16* gb = B_ + (col0 + (t >> 2)) * K_ + (t & 3) * 8;                         \
  u16* la = lds_a + w * 512;                                                         \
  u16* lb = lds_b + w * 512;                                                         \
  const int fr = lane & 15;                                                          \
  const int fk = (lane >> 4) * 8;                                                    \
  for (int kt = 0; kt < K_; kt += 32) {                                              \
    __syncthreads();                                                                 \
    gload16(ga + kt, la);                                                            \
    gload16(ga + (size_t)64 * K_ + kt, la + 2048);                                   \
    gload16(gb + kt, lb);                                                            \
    gload16(gb + (size_t)64 * K_ + kt, lb + 2048);                                   \
    __syncthreads();                                                                 \
    bf16x8 af[4], bfr[4];                                                            \
    _Pragma("unroll") for (int i = 0; i < 4; ++i)                                    \
      af[i] = ld8(&lds_a[(wr * 64 + i * 16 + fr) * 32 + fk]);                        \
    _Pragma("unroll") for (int j = 0; j < 4; ++j)                                    \
      bfr[j] = ld8(&lds_b[(wc * 64 + j * 16 + fr) * 32 + fk]);                       \
    _Pragma("unroll") for (int i = 0; i < 4; ++i)                                    \
      _Pragma("unroll") for (int j = 0; j < 4; ++j)                                  \
        acc[i][j] = __builtin_amdgcn_mfma_f32_16x16x32_bf16(af[i], bfr[j], acc[i][j], 0, 0, 0); \
  }                                                                                  \
  const int er = (lane >> 4) * 4, ec = lane & 15;

// Q/K/V projections fused with the f32->bf16 input cast. Race-hardened:
// explicit waitcnt + sched_barrier fences pin the ds_write/gload_lds between
// the barriers that protect them.
// z=0: Q * QSCALE. z=1: K with per-row chunk XOR. z=2: V^T + PV key perm + XOR.
__global__ __launch_bounds__(256)
void gemm_qkv(const float* __restrict__ xq, const float* __restrict__ xk,
              const float* __restrict__ xv, const u16* __restrict__ Ball,
              u16* __restrict__ Call) {
  const int g = (blockIdx.x & 7) * 192 + (blockIdx.x >> 3);
  const int bx = g & 7, by = (g >> 3) & 63, z = g >> 9;
  const float* A = (z == 0) ? xq : (z == 1) ? xk : xv;
  const u16* B = Ball + (size_t)z * 1024 * 1024;
  u16* C = Call + (size_t)z * 8192 * 1024;

  __shared__ alignas(16) u16 lds_a[128 * 32];
  __shared__ alignas(16) u16 lds_b[128 * 32];
  const int t = threadIdx.x;
  const int w = t >> 6, lane = t & 63;
  const int wr = w >> 1, wc = w & 1;
  const size_t row0 = (size_t)by * 128;
  const size_t col0 = (size_t)bx * 128;

  f32x4 acc[4][4];
#pragma unroll
  for (int i = 0; i < 4; ++i)
#pragma unroll
    for (int j = 0; j < 4; ++j) acc[i][j] = {0.f, 0.f, 0.f, 0.f};

  const float* ga = A + (row0 + (t >> 2)) * 1024 + (t & 3) * 8;
  const u16* gb = B + (col0 + (t >> 2)) * 1024 + (t & 3) * 8;
  u16* la_w = lds_a + t * 8;            // same LDS image as gload_lds staging
  u16* lb = lds_b + w * 512;

  const int fr = lane & 15;
  const int fk = (lane >> 4) * 8;

  // prologue: A f32 regs for kt=0
  float4 a0 = *reinterpret_cast<const float4*>(ga);
  float4 a1 = *reinterpret_cast<const float4*>(ga + 4);
  float4 a2 = *reinterpret_cast<const float4*>(ga + (size_t)64 * 1024);
  float4 a3 = *reinterpret_cast<const float4*>(ga + (size_t)64 * 1024 + 4);

  for (int kt = 0; kt < 1024; kt += 32) {
    __syncthreads();                 // readers of lds done
    SCHED_FENCE();                   // nothing below may hoist above the barrier
    {
      bf16x8 aw0, aw1;
      aw0[0] = (__bf16)a0.x; aw0[1] = (__bf16)a0.y; aw0[2] = (__bf16)a0.z; aw0[3] = (__bf16)a0.w;
      aw0[4] = (__bf16)a1.x; aw0[5] = (__bf16)a1.y; aw0[6] = (__bf16)a1.z; aw0[7] = (__bf16)a1.w;
      aw1[0] = (__bf16)a2.x; aw1[1] = (__bf16)a2.y; aw1[2] = (__bf16)a2.z; aw1[3] = (__bf16)a2.w;
      aw1[4] = (__bf16)a3.x; aw1[5] = (__bf16)a3.y; aw1[6] = (__bf16)a3.z; aw1[7] = (__bf16)a3.w;
      *reinterpret_cast<bf16x8*>(la_w) = aw0;
      *reinterpret_cast<bf16x8*>(la_w + 2048) = aw1;
    }
    gload16(gb + kt, lb);
    gload16(gb + (size_t)64 * 1024 + kt, lb + 2048);
    asm volatile("s_waitcnt vmcnt(0) lgkmcnt(0)" ::: "memory");  // DMA + ds_write landed
    SCHED_FENCE();
    __syncthreads();                 // tile ready for all waves
    SCHED_FENCE();

    // prefetch next A chunk (consumed after next barrier)
    const int nkt = (kt + 32) & 1023;  // wrap: last prefetch re-reads kt=0 (unused)
    a0 = *reinterpret_cast<const float4*>(ga + nkt);
    a1 = *reinterpret_cast<const float4*>(ga + nkt + 4);
    a2 = *reinterpret_cast<const float4*>(ga + (size_t)64 * 1024 + nkt);
    a3 = *reinterpret_cast<const float4*>(ga + (size_t)64 * 1024 + nkt + 4);

    bf16x8 af[4], bfr[4];
#pragma unroll
    for (int i = 0; i < 4; ++i) af[i] = ld8(&lds_a[(wr * 64 + i * 16 + fr) * 32 + fk]);
#pragma unroll
    for (int j = 0; j < 4; ++j) bfr[j] = ld8(&lds_b[(wc * 64 + j * 16 + fr) * 32 + fk]);
#pragma unroll
    for (int i = 0; i < 4; ++i)
#pragma unroll
      for (int j = 0; j < 4; ++j)
        acc[i][j] = __builtin_amdgcn_mfma_f32_16x16x32_bf16(af[i], bfr[j], acc[i][j], 0, 0, 0);
  }

  const int er = (lane >> 4) * 4, ec = lane & 15;
#pragma unroll
  for (int i = 0; i < 4; ++i)
#pragma unroll
    for (int j = 0; j < 4; ++j) {
      const size_t row = row0 + wr * 64 + i * 16 + er;
      const size_t col = col0 + wc * 64 + j * 16 + ec;
      if (z == 0) {
#pragma unroll
        for (int r = 0; r < 4; ++r)
          C[(row + r) * 1024 + col] = f2bf(acc[i][j][r] * QSCALE);
      } else if (z == 1) {
        // K: swizzle dim chunk (8 dims = 16B) within head by key&7
#pragma unroll
        for (int r = 0; r < 4; ++r) {
          const size_t n = row + r;
          const size_t colswz = (col & ~(size_t)63) |
                                ((col & 63) ^ (((n & 7) << 3)));
          C[n * 1024 + colswz] = f2bf(acc[i][j][r]);
        }
      } else {
        // V^T per head: PV key permutation + key-chunk XOR by dim&7.
        ushort4 o4;
        o4.x = f2bf(acc[i][j][0]); o4.y = f2bf(acc[i][j][1]);
        o4.z = f2bf(acc[i][j][2]); o4.w = f2bf(acc[i][j][3]);
        const size_t nloc = row & 2047;
        const size_t d = col & 63;
        size_t pos = (nloc & ~(size_t)31) | (((nloc >> 2) & 3) << 3) |
                     (((nloc >> 4) & 1) << 2) | (nloc & 3);
        pos ^= (d & 7) << 3;
        const size_t idx = (((row >> 11) * 16 + (col >> 6)) * 64 + d) * 2048 + pos;
        *reinterpret_cast<ushort4*>(&C[idx]) = o4;
      }
    }
}

// Out-projection: f32 out + bias; 1-D grid, XCD swizzle (512 = 8*64).
__global__ __launch_bounds__(256)
void gemm_out(const u16* __restrict__ A, const u16* __restrict__ B,
              float* __restrict__ Cf, const float* __restrict__ bias) {
  const int g = (blockIdx.x & 7) * 64 + (blockIdx.x >> 3);
  const int bx = g & 7, by = g >> 3;
  GEMM_CORE(A, B, 1024, bx, by)
#pragma unroll
  for (int i = 0; i < 4; ++i)
#pragma unroll
    for (int j = 0; j < 4; ++j) {
      const size_t row = row0 + wr * 64 + i * 16 + er;
      const size_t col = col0 + wc * 64 + j * 16 + ec;
#pragma unroll
      for (int r = 0; r < 4; ++r)
        Cf[(row + r) * 1024 + col] = acc[i][j][r] + bias[col];
    }
}

// Flash attention v9: 512 threads (8 waves), QBLK=256, swapped QK^T, raw-exp2
// softmax, ones-column MFMA row-sum, gload_lds double-buffer — RACE-HARDENED:
// explicit vmcnt drain + sched fences pin the DMA issue between the barriers.
__global__ __launch_bounds__(512)
void flash_attn(const u16* __restrict__ Q, const u16* __restrict__ Km,
                const u16* __restrict__ Vt, u16* __restrict__ O) {
  // XCD swizzle: consecutive qt-blocks of same (b,h) -> same XCD
  const int o_blk = (blockIdx.x & 7) * 64 + (blockIdx.x >> 3);
  const int qt = o_blk & 7, h = (o_blk >> 3) & 15, b = o_blk >> 7;
  const int t = threadIdx.x;
  const int w = t >> 6, lane = t & 63;
  const int l16 = lane & 15, lh = lane >> 4;

  __shared__ alignas(16) u16 kt_lds[2][64][64];   // [buf][key][dim-chunk-swz]
  __shared__ alignas(16) u16 vt_lds[2][64][64];   // [buf][dim][key-pos-swz]

  const size_t base_qk = ((size_t)b * 2048) * 1024 + (size_t)h * 64;
  const size_t base_vt = ((size_t)(b * 16 + h)) * 64 * 2048;

  bf16x8 qf[2][2];
#pragma unroll
  for (int g = 0; g < 2; ++g) {
    const size_t qrow = (size_t)qt * 256 + (w * 2 + g) * 16 + l16;
    const u16* qp = Q + base_qk + qrow * 1024 + lh * 8;
    qf[g][0] = ld8(qp);
    qf[g][1] = ld8(qp + 32);
  }

  bf16x8 vones;
#pragma unroll
  for (int i = 0; i < 8; ++i) vones[i] = (__bf16)1.0f;

  f32x4 o_acc[2][4];
  f32x4 o_sum[2];
#pragma unroll
  for (int g = 0; g < 2; ++g) {
#pragma unroll
    for (int j = 0; j < 4; ++j) o_acc[g][j] = {0.f, 0.f, 0.f, 0.f};
    o_sum[g] = {0.f, 0.f, 0.f, 0.f};
  }

  // gload_lds staging: thread t covers row t>>3, chunk (t&7)*8 (16B/lane);
  // LDS dest = wave-uniform base + lane*16B == linear [row][64] layout.
  const int srow = t >> 3;
  const int schk = (t & 7) * 8;
  const u16* kg = Km + base_qk + (size_t)srow * 1024 + schk;
  const u16* vg = Vt + base_vt + (size_t)srow * 2048 + schk;
  u16* kl0 = &kt_lds[0][0][0] + w * 512;
  u16* kl1 = &kt_lds[1][0][0] + w * 512;
  u16* vl0 = &vt_lds[0][0][0] + w * 512;
  u16* vl1 = &vt_lds[1][0][0] + w * 512;

  // prologue: issue tile 0 into buf 0
  gload16(kg, kl0);
  gload16(vg, vl0);

  const int xo = (l16 & 7) << 3;  // fragment-read XOR (row&7 == l16&7)

  for (int it = 0; it < 32; ++it) {
    const int cur = it & 1;
    // drain this wave's DMA + pin ordering, then block-wide barrier
    asm volatile("s_waitcnt vmcnt(0)" ::: "memory");
    SCHED_FENCE();
    __syncthreads();
    SCHED_FENCE();

    if (it != 31) {
      const int nkv = (it + 1) * 64;
      gload16(kg + (size_t)nkv * 1024, cur ? kl0 : kl1);
      gload16(vg + nkv, cur ? vl0 : vl1);
    }
    SCHED_FENCE();  // DMA issue may not migrate into/over the barrier region

    // S^T = K Q^T for both q-row groups; kf shared across g
    f32x4 s[2][4];
#pragma unroll
    for (int g = 0; g < 2; ++g)
#pragma unroll
      for (int j = 0; j < 4; ++j) s[g][j] = {0.f, 0.f, 0.f, 0.f};
    __builtin_amdgcn_s_setprio(1);
#pragma unroll
    for (int j = 0; j < 4; ++j)
#pragma unroll
      for (int ks = 0; ks < 2; ++ks) {
        bf16x8 kf = ld8(&kt_lds[cur][j * 16 + l16][(ks * 32 + lh * 8) ^ xo]);
        s[0][j] = __builtin_amdgcn_mfma_f32_16x16x32_bf16(kf, qf[0][ks], s[0][j], 0, 0, 0);
        s[1][j] = __builtin_amdgcn_mfma_f32_16x16x32_bf16(kf, qf[1][ks], s[1][j], 0, 0, 0);
      }
    __builtin_amdgcn_s_setprio(0);

    // P = exp2(S) raw (shift-invariant softmax; no max tracking);
    // pack in-register: pa[g][c] slot i = key 16*(2c+(i>>2)) + 4lh + (i&3)
    bf16x8 pa[2][2];
#pragma unroll
    for (int g = 0; g < 2; ++g)
#pragma unroll
      for (int j = 0; j < 4; ++j)
#pragma unroll
        for (int r = 0; r < 4; ++r)
          s[g][j][r] = EXP2F(s[g][j][r]);
#pragma unroll
    for (int g = 0; g < 2; ++g)
#pragma unroll
      for (int c = 0; c < 2; ++c)
#pragma unroll
        for (int i = 0; i < 8; ++i)
          pa[g][c][i] = (__bf16)s[g][2 * c + (i >> 2)][i & 3];

    // PV + ones-column row-sum; vf shared across g
    __builtin_amdgcn_s_setprio(1);
#pragma unroll
    for (int c = 0; c < 2; ++c) {
      o_sum[0] = __builtin_amdgcn_mfma_f32_16x16x32_bf16(pa[0][c], vones, o_sum[0], 0, 0, 0);
      o_sum[1] = __builtin_amdgcn_mfma_f32_16x16x32_bf16(pa[1][c], vones, o_sum[1], 0, 0, 0);
#pragma unroll
      for (int jd = 0; jd < 4; ++jd) {
        bf16x8 vf = ld8(&vt_lds[cur][jd * 16 + l16][(c * 32 + lh * 8) ^ xo]);
        o_acc[0][jd] = __builtin_amdgcn_mfma_f32_16x16x32_bf16(pa[0][c], vf, o_acc[0][jd], 0, 0, 0);
        o_acc[1][jd] = __builtin_amdgcn_mfma_f32_16x16x32_bf16(pa[1][c], vf, o_acc[1][jd], 0, 0, 0);
      }
    }
    __builtin_amdgcn_s_setprio(0);
  }

#pragma unroll
  for (int g = 0; g < 2; ++g) {
    float linv[4];
#pragma unroll
    for (int r = 0; r < 4; ++r) linv[r] = 1.0f / o_sum[g][r];  // already PV-row layout
    const size_t orow0 = (size_t)b * 2048 + (size_t)qt * 256 + (w * 2 + g) * 16;
#pragma unroll
    for (int jd = 0; jd < 4; ++jd) {
      const int col = h * 64 + jd * 16 + l16;
#pragma unroll
      for (int r = 0; r < 4; ++r)
        O[(orow0 + lh * 4 + r) * 1024 + col] = f2bf(o_acc[g][jd][r] * linv[r]);
    }
  }
}

extern "C" void kernel_launch(void* const* d_in, const int* in_sizes, int n_in,
                              void* d_out, int out_size, void* d_ws, size_t ws_size,
                              hipStream_t stream) {
  const float* xq = (const float*)d_in[0];
  const float* xk = (const float*)d_in[1];
  const float* xv = (const float*)d_in[2];
  const float* Wq = (const float*)d_in[3];
  const float* Wk = (const float*)d_in[4];
  const float* Wv = (const float*)d_in[5];
  const float* Wo = (const float*)d_in[6];
  const float* bo = (const float*)d_in[7];
  float* out = (float*)d_out;

  const size_t X = (size_t)8192 * 1024;
  const size_t W = (size_t)1024 * 1024;

  u16* p = (u16*)d_ws;
  u16* attn_bf = p; p += X;            // attention output (bf16)
  u16* w_bf  = p; p += 4 * W;          // Wq | Wk | Wv | Wo
  u16* qkv   = p; p += 3 * X;          // Q | K(swz) | V^T(swz) (contiguous)

  dim3 blk(256);
  cast4_f32_to_bf16<<<dim3(1024, 4), blk, 0, stream>>>(Wq, Wk, Wv, Wo, w_bf, (int)(W / 4));

  gemm_qkv<<<dim3(1536), blk, 0, stream>>>(xq, xk, xv, w_bf, qkv);

  flash_attn<<<dim3(512), dim3(512), 0, stream>>>(qkv, qkv + X, qkv + 2 * X, attn_bf);

  gemm_out<<<dim3(512), blk, 0, stream>>>(attn_bf, w_bf + 3 * W, out, bo);
}

// Round 14
// 192.596 us; speedup vs baseline: 1.7371x; 1.7371x over previous
//
#include <hip/hip_runtime.h>

typedef unsigned short u16;
using bf16x8 = __attribute__((ext_vector_type(8))) __bf16;
using f32x4  = __attribute__((ext_vector_type(4))) float;

// SCALE * log2(e): softmax runs in exp2 domain
#define QSCALE 0.18033688011f

#define EXP2F(x) __builtin_amdgcn_exp2f(x)
#define SCHED_FENCE() __builtin_amdgcn_sched_barrier(0)

__device__ __forceinline__ u16 f2bf(float f) {
  union { float f; unsigned int u; } x; x.f = f;
  unsigned int r = x.u + 0x7FFFu + ((x.u >> 16) & 1u);
  return (u16)(r >> 16);
}

__device__ __forceinline__ bf16x8 ld8(const u16* p) {
  return *reinterpret_cast<const bf16x8*>(p);
}

__device__ __forceinline__ void gload16(const void* g, void* l) {
  __builtin_amdgcn_global_load_lds(
      (const __attribute__((address_space(1))) unsigned int*)g,
      (__attribute__((address_space(3))) unsigned int*)l, 16, 0, 0);
}

__global__ void cast4_f32_to_bf16(const float* __restrict__ a, const float* __restrict__ b,
                                  const float* __restrict__ c, const float* __restrict__ d,
                                  u16* __restrict__ out, int n4) {
  const int y = blockIdx.y;
  const int i = blockIdx.x * 256 + threadIdx.x;
  if (i >= n4) return;
  const float* src = (y == 0) ? a : (y == 1) ? b : (y == 2) ? c : d;
  const float4 v = reinterpret_cast<const float4*>(src)[i];
  ushort4 o;
  o.x = f2bf(v.x); o.y = f2bf(v.y); o.z = f2bf(v.z); o.w = f2bf(v.w);
  reinterpret_cast<ushort4*>(out + (size_t)y * n4 * 4)[i] = o;
}

// ---- shared GEMM core (m97 structure: 128x128 tile, BK=32, gload_lds w=16) ----
// bx/by supplied by caller (XCD-swizzled). Known-good shape; unchanged.
#define GEMM_CORE(A_, B_, K_, BX_, BY_)                                              \
  __shared__ alignas(16) u16 lds_a[128 * 32];                                        \
  __shared__ alignas(16) u16 lds_b[128 * 32];                                        \
  const int t = threadIdx.x;                                                         \
  const int w = t >> 6, lane = t & 63;                                               \
  const int wr = w >> 1, wc = w & 1;                                                 \
  const size_t row0 = (size_t)(BY_) * 128;                                           \
  const size_t col0 = (size_t)(BX_) * 128;                                           \
  f32x4 acc[4][4];                                                                   \
  _Pragma("unroll") for (int i = 0; i < 4; ++i)                                      \
    _Pragma("unroll") for (int j = 0; j < 4; ++j) acc[i][j] = {0.f, 0.f, 0.f, 0.f};  \
  const u16* ga = A_ + (row0 + (t >> 2)) * K_ + (t & 3) * 8;                         \
  const u16* gb = B_ + (col0 + (t >> 2)) * K_ + (t & 3) * 8;                         \
  u16* la = lds_a + w * 512;                                                         \
  u16* lb = lds_b + w * 512;                                                         \
  const int fr = lane & 15;                                                          \
  const int fk = (lane >> 4) * 8;                                                    \
  for (int kt = 0; kt < K_; kt += 32) {                                              \
    __syncthreads();                                                                 \
    gload16(ga + kt, la);                                                            \
    gload16(ga + (size_t)64 * K_ + kt, la + 2048);                                   \
    gload16(gb + kt, lb);                                                            \
    gload16(gb + (size_t)64 * K_ + kt, lb + 2048);                                   \
    asm volatile("s_waitcnt vmcnt(0)" ::: "memory");                                 \
    __syncthreads();                                                                 \
    bf16x8 af[4], bfr[4];                                                            \
    _Pragma("unroll") for (int i = 0; i < 4; ++i)                                    \
      af[i] = ld8(&lds_a[(wr * 64 + i * 16 + fr) * 32 + fk]);                        \
    _Pragma("unroll") for (int j = 0; j < 4; ++j)                                    \
      bfr[j] = ld8(&lds_b[(wc * 64 + j * 16 + fr) * 32 + fk]);                       \
    _Pragma("unroll") for (int i = 0; i < 4; ++i)                                    \
      _Pragma("unroll") for (int j = 0; j < 4; ++j)                                  \
        acc[i][j] = __builtin_amdgcn_mfma_f32_16x16x32_bf16(af[i], bfr[j], acc[i][j], 0, 0, 0); \
  }                                                                                  \
  const int er = (lane >> 4) * 4, ec = lane & 15;

// Q/K/V projections with fused f32->bf16 input cast, RACE-SAFE staging:
// BOTH operands via pure global_load_lds (no ds_write mixing). A staged as raw
// f32 (4 issues, 16 KB tile) with bank-conflict fix via PRE-SWIZZLED per-lane
// global source chunk (LDS stays linear); fragment reads apply the same XOR and
// convert f32->bf16 in-register.
// z=0: Q * QSCALE. z=1: K with per-row chunk XOR. z=2: V^T + PV key perm + XOR.
__global__ __launch_bounds__(256)
void gemm_qkv(const float* __restrict__ xq, const float* __restrict__ xk,
              const float* __restrict__ xv, const u16* __restrict__ Ball,
              u16* __restrict__ Call) {
  const int g = (blockIdx.x & 7) * 192 + (blockIdx.x >> 3);
  const int bx = g & 7, by = (g >> 3) & 63, z = g >> 9;
  const float* A = (z == 0) ? xq : (z == 1) ? xk : xv;
  const u16* B = Ball + (size_t)z * 1024 * 1024;
  u16* C = Call + (size_t)z * 8192 * 1024;

  __shared__ alignas(16) float lds_af[128 * 32];  // f32 A tile, chunk-XOR image
  __shared__ alignas(16) u16 lds_b[128 * 32];
  const int t = threadIdx.x;
  const int w = t >> 6, lane = t & 63;
  const int wr = w >> 1, wc = w & 1;
  const size_t row0 = (size_t)by * 128;
  const size_t col0 = (size_t)bx * 128;

  f32x4 acc[4][4];
#pragma unroll
  for (int i = 0; i < 4; ++i)
#pragma unroll
    for (int j = 0; j < 4; ++j) acc[i][j] = {0.f, 0.f, 0.f, 0.f};

  // A staging: thread t -> tile row (i*32 + t>>3), source chunk (t&7)^(row&7).
  // LDS linear f32 [row][32]; LDS(row,c) holds global chunk c^(row&7).
  const int arow = t >> 3;
  const int achk = (t & 7) ^ (arow & 7);
  const float* gaf = A + (row0 + arow) * 1024 + achk * 4;
  // B staging: m97 pattern (bf16, linear).
  const u16* gb = B + (col0 + (t >> 2)) * 1024 + (t & 3) * 8;
  float* laf = lds_af + w * 256;   // wave-uniform; lane*16B implicit
  u16* lb = lds_b + w * 512;

  const int fr = lane & 15;
  const int fk = (lane >> 4) * 8;
  const int fx = fr & 7;           // fragment-read chunk XOR

  for (int kt = 0; kt < 1024; kt += 32) {
    __syncthreads();
    gload16(gaf + kt, laf);
    gload16(gaf + kt + 32 * 1024, laf + 1024);
    gload16(gaf + kt + 64 * 1024, laf + 2048);
    gload16(gaf + kt + 96 * 1024, laf + 3072);
    gload16(gb + kt, lb);
    gload16(gb + (size_t)64 * 1024 + kt, lb + 2048);
    asm volatile("s_waitcnt vmcnt(0)" ::: "memory");
    __syncthreads();

    bf16x8 af[4], bfr[4];
#pragma unroll
    for (int i = 0; i < 4; ++i) {
      const int row = wr * 64 + i * 16 + fr;
      const int c0 = fk >> 2;      // {0,2,4,6}
      f32x4 lo = *reinterpret_cast<const f32x4*>(&lds_af[row * 32 + ((c0 ^ fx) << 2)]);
      f32x4 hi = *reinterpret_cast<const f32x4*>(&lds_af[row * 32 + (((c0 + 1) ^ fx) << 2)]);
      af[i][0] = (__bf16)lo[0]; af[i][1] = (__bf16)lo[1];
      af[i][2] = (__bf16)lo[2]; af[i][3] = (__bf16)lo[3];
      af[i][4] = (__bf16)hi[0]; af[i][5] = (__bf16)hi[1];
      af[i][6] = (__bf16)hi[2]; af[i][7] = (__bf16)hi[3];
    }
#pragma unroll
    for (int j = 0; j < 4; ++j)
      bfr[j] = ld8(&lds_b[(wc * 64 + j * 16 + fr) * 32 + fk]);
#pragma unroll
    for (int i = 0; i < 4; ++i)
#pragma unroll
      for (int j = 0; j < 4; ++j)
        acc[i][j] = __builtin_amdgcn_mfma_f32_16x16x32_bf16(af[i], bfr[j], acc[i][j], 0, 0, 0);
  }

  const int er = (lane >> 4) * 4, ec = lane & 15;
#pragma unroll
  for (int i = 0; i < 4; ++i)
#pragma unroll
    for (int j = 0; j < 4; ++j) {
      const size_t row = row0 + wr * 64 + i * 16 + er;
      const size_t col = col0 + wc * 64 + j * 16 + ec;
      if (z == 0) {
#pragma unroll
        for (int r = 0; r < 4; ++r)
          C[(row + r) * 1024 + col] = f2bf(acc[i][j][r] * QSCALE);
      } else if (z == 1) {
        // K: swizzle dim chunk (8 dims = 16B) within head by key&7
#pragma unroll
        for (int r = 0; r < 4; ++r) {
          const size_t n = row + r;
          const size_t colswz = (col & ~(size_t)63) |
                                ((col & 63) ^ (((n & 7) << 3)));
          C[n * 1024 + colswz] = f2bf(acc[i][j][r]);
        }
      } else {
        // V^T per head: PV key permutation + key-chunk XOR by dim&7.
        ushort4 o4;
        o4.x = f2bf(acc[i][j][0]); o4.y = f2bf(acc[i][j][1]);
        o4.z = f2bf(acc[i][j][2]); o4.w = f2bf(acc[i][j][3]);
        const size_t nloc = row & 2047;
        const size_t d = col & 63;
        size_t pos = (nloc & ~(size_t)31) | (((nloc >> 2) & 3) << 3) |
                     (((nloc >> 4) & 1) << 2) | (nloc & 3);
        pos ^= (d & 7) << 3;
        const size_t idx = (((row >> 11) * 16 + (col >> 6)) * 64 + d) * 2048 + pos;
        *reinterpret_cast<ushort4*>(&C[idx]) = o4;
      }
    }
}

// Out-projection: f32 out + bias; 1-D grid, XCD swizzle (512 = 8*64).
__global__ __launch_bounds__(256)
void gemm_out(const u16* __restrict__ A, const u16* __restrict__ B,
              float* __restrict__ Cf, const float* __restrict__ bias) {
  const int g = (blockIdx.x & 7) * 64 + (blockIdx.x >> 3);
  const int bx = g & 7, by = g >> 3;
  GEMM_CORE(A, B, 1024, bx, by)
#pragma unroll
  for (int i = 0; i < 4; ++i)
#pragma unroll
    for (int j = 0; j < 4; ++j) {
      const size_t row = row0 + wr * 64 + i * 16 + er;
      const size_t col = col0 + wc * 64 + j * 16 + ec;
#pragma unroll
      for (int r = 0; r < 4; ++r)
        Cf[(row + r) * 1024 + col] = acc[i][j][r] + bias[col];
    }
}

// Flash attention v9 (round-13, race-hardened, KEPT AS-IS): 512 threads, QBLK=256,
// swapped QK^T, raw-exp2 softmax, ones-column MFMA row-sum, gload_lds dbuf with
// explicit vmcnt drain + sched fences.
__global__ __launch_bounds__(512)
void flash_attn(const u16* __restrict__ Q, const u16* __restrict__ Km,
                const u16* __restrict__ Vt, u16* __restrict__ O) {
  // XCD swizzle: consecutive qt-blocks of same (b,h) -> same XCD
  const int o_blk = (blockIdx.x & 7) * 64 + (blockIdx.x >> 3);
  const int qt = o_blk & 7, h = (o_blk >> 3) & 15, b = o_blk >> 7;
  const int t = threadIdx.x;
  const int w = t >> 6, lane = t & 63;
  const int l16 = lane & 15, lh = lane >> 4;

  __shared__ alignas(16) u16 kt_lds[2][64][64];   // [buf][key][dim-chunk-swz]
  __shared__ alignas(16) u16 vt_lds[2][64][64];   // [buf][dim][key-pos-swz]

  const size_t base_qk = ((size_t)b * 2048) * 1024 + (size_t)h * 64;
  const size_t base_vt = ((size_t)(b * 16 + h)) * 64 * 2048;

  bf16x8 qf[2][2];
#pragma unroll
  for (int g = 0; g < 2; ++g) {
    const size_t qrow = (size_t)qt * 256 + (w * 2 + g) * 16 + l16;
    const u16* qp = Q + base_qk + qrow * 1024 + lh * 8;
    qf[g][0] = ld8(qp);
    qf[g][1] = ld8(qp + 32);
  }

  bf16x8 vones;
#pragma unroll
  for (int i = 0; i < 8; ++i) vones[i] = (__bf16)1.0f;

  f32x4 o_acc[2][4];
  f32x4 o_sum[2];
#pragma unroll
  for (int g = 0; g < 2; ++g) {
#pragma unroll
    for (int j = 0; j < 4; ++j) o_acc[g][j] = {0.f, 0.f, 0.f, 0.f};
    o_sum[g] = {0.f, 0.f, 0.f, 0.f};
  }

  const int srow = t >> 3;
  const int schk = (t & 7) * 8;
  const u16* kg = Km + base_qk + (size_t)srow * 1024 + schk;
  const u16* vg = Vt + base_vt + (size_t)srow * 2048 + schk;
  u16* kl0 = &kt_lds[0][0][0] + w * 512;
  u16* kl1 = &kt_lds[1][0][0] + w * 512;
  u16* vl0 = &vt_lds[0][0][0] + w * 512;
  u16* vl1 = &vt_lds[1][0][0] + w * 512;

  // prologue: issue tile 0 into buf 0
  gload16(kg, kl0);
  gload16(vg, vl0);

  const int xo = (l16 & 7) << 3;  // fragment-read XOR (row&7 == l16&7)

  for (int it = 0; it < 32; ++it) {
    const int cur = it & 1;
    asm volatile("s_waitcnt vmcnt(0)" ::: "memory");
    SCHED_FENCE();
    __syncthreads();
    SCHED_FENCE();

    if (it != 31) {
      const int nkv = (it + 1) * 64;
      gload16(kg + (size_t)nkv * 1024, cur ? kl0 : kl1);
      gload16(vg + nkv, cur ? vl0 : vl1);
    }
    SCHED_FENCE();

    // S^T = K Q^T for both q-row groups; kf shared across g
    f32x4 s[2][4];
#pragma unroll
    for (int g = 0; g < 2; ++g)
#pragma unroll
      for (int j = 0; j < 4; ++j) s[g][j] = {0.f, 0.f, 0.f, 0.f};
    __builtin_amdgcn_s_setprio(1);
#pragma unroll
    for (int j = 0; j < 4; ++j)
#pragma unroll
      for (int ks = 0; ks < 2; ++ks) {
        bf16x8 kf = ld8(&kt_lds[cur][j * 16 + l16][(ks * 32 + lh * 8) ^ xo]);
        s[0][j] = __builtin_amdgcn_mfma_f32_16x16x32_bf16(kf, qf[0][ks], s[0][j], 0, 0, 0);
        s[1][j] = __builtin_amdgcn_mfma_f32_16x16x32_bf16(kf, qf[1][ks], s[1][j], 0, 0, 0);
      }
    __builtin_amdgcn_s_setprio(0);

    // P = exp2(S) raw; pack: pa[g][c] slot i = key 16*(2c+(i>>2)) + 4lh + (i&3)
    bf16x8 pa[2][2];
#pragma unroll
    for (int g = 0; g < 2; ++g)
#pragma unroll
      for (int j = 0; j < 4; ++j)
#pragma unroll
        for (int r = 0; r < 4; ++r)
          s[g][j][r] = EXP2F(s[g][j][r]);
#pragma unroll
    for (int g = 0; g < 2; ++g)
#pragma unroll
      for (int c = 0; c < 2; ++c)
#pragma unroll
        for (int i = 0; i < 8; ++i)
          pa[g][c][i] = (__bf16)s[g][2 * c + (i >> 2)][i & 3];

    // PV + ones-column row-sum; vf shared across g
    __builtin_amdgcn_s_setprio(1);
#pragma unroll
    for (int c = 0; c < 2; ++c) {
      o_sum[0] = __builtin_amdgcn_mfma_f32_16x16x32_bf16(pa[0][c], vones, o_sum[0], 0, 0, 0);
      o_sum[1] = __builtin_amdgcn_mfma_f32_16x16x32_bf16(pa[1][c], vones, o_sum[1], 0, 0, 0);
#pragma unroll
      for (int jd = 0; jd < 4; ++jd) {
        bf16x8 vf = ld8(&vt_lds[cur][jd * 16 + l16][(c * 32 + lh * 8) ^ xo]);
        o_acc[0][jd] = __builtin_amdgcn_mfma_f32_16x16x32_bf16(pa[0][c], vf, o_acc[0][jd], 0, 0, 0);
        o_acc[1][jd] = __builtin_amdgcn_mfma_f32_16x16x32_bf16(pa[1][c], vf, o_acc[1][jd], 0, 0, 0);
      }
    }
    __builtin_amdgcn_s_setprio(0);
  }

#pragma unroll
  for (int g = 0; g < 2; ++g) {
    float linv[4];
#pragma unroll
    for (int r = 0; r < 4; ++r) linv[r] = 1.0f / o_sum[g][r];  // already PV-row layout
    const size_t orow0 = (size_t)b * 2048 + (size_t)qt * 256 + (w * 2 + g) * 16;
#pragma unroll
    for (int jd = 0; jd < 4; ++jd) {
      const int col = h * 64 + jd * 16 + l16;
#pragma unroll
      for (int r = 0; r < 4; ++r)
        O[(orow0 + lh * 4 + r) * 1024 + col] = f2bf(o_acc[g][jd][r] * linv[r]);
    }
  }
}

extern "C" void kernel_launch(void* const* d_in, const int* in_sizes, int n_in,
                              void* d_out, int out_size, void* d_ws, size_t ws_size,
                              hipStream_t stream) {
  const float* xq = (const float*)d_in[0];
  const float* xk = (const float*)d_in[1];
  const float* xv = (const float*)d_in[2];
  const float* Wq = (const float*)d_in[3];
  const float* Wk = (const float*)d_in[4];
  const float* Wv = (const float*)d_in[5];
  const float* Wo = (const float*)d_in[6];
  const float* bo = (const float*)d_in[7];
  float* out = (float*)d_out;

  const size_t X = (size_t)8192 * 1024;
  const size_t W = (size_t)1024 * 1024;

  u16* p = (u16*)d_ws;
  u16* attn_bf = p; p += X;            // attention output (bf16)
  u16* w_bf  = p; p += 4 * W;          // Wq | Wk | Wv | Wo
  u16* qkv   = p; p += 3 * X;          // Q | K(swz) | V^T(swz) (contiguous)

  dim3 blk(256);
  cast4_f32_to_bf16<<<dim3(1024, 4), blk, 0, stream>>>(Wq, Wk, Wv, Wo, w_bf, (int)(W / 4));

  gemm_qkv<<<dim3(1536), blk, 0, stream>>>(xq, xk, xv, w_bf, qkv);

  flash_attn<<<dim3(512), dim3(512), 0, stream>>>(qkv, qkv + X, qkv + 2 * X, attn_bf);

  gemm_out<<<dim3(512), blk, 0, stream>>>(attn_bf, w_bf + 3 * W, out, bo);
}